// Round 1
// baseline (565.716 us; speedup 1.0000x reference)
//
#include <hip/hip_runtime.h>
#include <hip/hip_bf16.h>
#include <stdint.h>

typedef unsigned short u16;

#define NB 2
#define NC 128
#define NHD 4      // heads
#define HD 32      // head dim
#define NN 3136    // H*W
#define NA 49      // agent tokens
#define SCALE 0.17677669529663687f  // 1/sqrt(32)

// ---------------------------------------------------------------------------
// dtype detection: sample 256 16-bit words (odd stride -> hits both halves of
// fp32 words). Genuine bf16 normals: ~all |v| in [1e-4,100]. fp32 reinterpret:
// low-half words have random exponents -> ~8% in range. Threshold 230.
__global__ void k_detect(const u16* __restrict__ raw, int* __restrict__ flag) {
    __shared__ int cnt;
    if (threadIdx.x == 0) cnt = 0;
    __syncthreads();
    u16 w = raw[threadIdx.x * 97];
    float f = __uint_as_float(((uint32_t)w) << 16);
    float a = fabsf(f);
    if (a >= 1e-4f && a <= 100.0f) atomicAdd(&cnt, 1);
    __syncthreads();
    if (threadIdx.x == 0) *flag = (cnt >= 230) ? 1 : 0;
}

__global__ void k_convert(const void* __restrict__ src, float* __restrict__ dst,
                          int n, const int* __restrict__ flag) {
    int i = blockIdx.x * 256 + threadIdx.x;
    if (i >= n) return;
    if (*flag) {
        u16 w = ((const u16*)src)[i];
        dst[i] = __uint_as_float(((uint32_t)w) << 16);
    } else {
        dst[i] = ((const float*)src)[i];
    }
}

// ---------------------------------------------------------------------------
// QKV: per batch GEMM [384x128] @ [128x3136]. 64x64 tile, 4x4 micro-tile.
// Writes q/k/v in [b][h][n][d] layout (d contiguous), float4 along d.
__global__ __launch_bounds__(256) void k_qkv(const float* __restrict__ xf,
                                             const float* __restrict__ wf,
                                             float* __restrict__ q,
                                             float* __restrict__ k,
                                             float* __restrict__ v) {
    __shared__ float wl[64][36];   // pad 36: 16B-aligned rows
    __shared__ float xl[32][68];
    int b  = blockIdx.z;
    int o0 = blockIdx.y * 64;
    int n0 = blockIdx.x * 64;
    int t  = threadIdx.x;
    int ty = t >> 4, tx = t & 15;
    float acc[4][4] = {};
    for (int kk = 0; kk < 4; ++kk) {
        __syncthreads();
#pragma unroll
        for (int j = 0; j < 2; ++j) {
            int idx = t + j * 256;           // 0..511
            int r = idx >> 3, c4 = (idx & 7) * 4;
            *(float4*)&wl[r][c4] = *(const float4*)&wf[(o0 + r) * NC + kk * 32 + c4];
        }
#pragma unroll
        for (int j = 0; j < 2; ++j) {
            int idx = t + j * 256;
            int r = idx >> 4, c4 = (idx & 15) * 4;
            *(float4*)&xl[r][c4] = *(const float4*)&xf[(b * NC + kk * 32 + r) * NN + n0 + c4];
        }
        __syncthreads();
#pragma unroll
        for (int c = 0; c < 32; ++c) {
            float a0 = wl[ty * 4 + 0][c], a1 = wl[ty * 4 + 1][c];
            float a2 = wl[ty * 4 + 2][c], a3 = wl[ty * 4 + 3][c];
            float4 b4 = *(float4*)&xl[c][tx * 4];
            acc[0][0] += a0 * b4.x; acc[0][1] += a0 * b4.y; acc[0][2] += a0 * b4.z; acc[0][3] += a0 * b4.w;
            acc[1][0] += a1 * b4.x; acc[1][1] += a1 * b4.y; acc[1][2] += a1 * b4.z; acc[1][3] += a1 * b4.w;
            acc[2][0] += a2 * b4.x; acc[2][1] += a2 * b4.y; acc[2][2] += a2 * b4.z; acc[2][3] += a2 * b4.w;
            acc[3][0] += a3 * b4.x; acc[3][1] += a3 * b4.y; acc[3][2] += a3 * b4.z; acc[3][3] += a3 * b4.w;
        }
    }
    // o = t*128 + h*32 + d ; 4 consecutive o share (t,h), d block 4-aligned
    int ob = o0 + ty * 4;
    int tq = ob >> 7, h = (ob >> 5) & 3, d0 = ob & 31;
    float* dst = (tq == 0) ? q : ((tq == 1) ? k : v);
#pragma unroll
    for (int j = 0; j < 4; ++j) {
        int n = n0 + tx * 4 + j;
        float4 val = make_float4(acc[0][j], acc[1][j], acc[2][j], acc[3][j]);
        *(float4*)&dst[((b * NHD + h) * NN + n) * HD + d0] = val;
    }
}

// ---------------------------------------------------------------------------
// agent tokens: 8x8 block mean of x -> [b][h][a][d]
__global__ void k_agent(const float* __restrict__ xf, float* __restrict__ ag) {
    int idx = blockIdx.x * 256 + threadIdx.x;
    if (idx >= NB * NC * NA) return;
    int b = idx / (NC * NA);
    int r = idx % (NC * NA);
    int c = r / NA;
    int a = r % NA;
    int ai = a / 7, aj = a % 7;
    const float* base = xf + (b * NC + c) * NN + ai * 8 * 56 + aj * 8;
    float s = 0.f;
#pragma unroll
    for (int u = 0; u < 8; ++u) {
        float4 v0 = *(const float4*)&base[u * 56];
        float4 v1 = *(const float4*)&base[u * 56 + 4];
        s += v0.x + v0.y + v0.z + v0.w + v1.x + v1.y + v1.z + v1.w;
    }
    int h = c >> 5, d = c & 31;
    ag[((b * NHD + h) * NA + a) * HD + d] = s * (1.f / 64.f);
}

// ---------------------------------------------------------------------------
// stage 1: per q-row softmax over 49 agents, q_compressed (pre-scaled for
// stage 2). One wave per row, 4 rows per block.
__global__ __launch_bounds__(256) void k_stage1(const float* __restrict__ q,
                                                const float* __restrict__ ag,
                                                float* __restrict__ qcs) {
    __shared__ float agl[NA][33];   // pad 33: conflict-free both read patterns
    __shared__ float pl[4][64];
    int b = blockIdx.z, h = blockIdx.y;
    int nb = blockIdx.x * 4;
    int t = threadIdx.x;
    const float* agb = ag + (b * NHD + h) * NA * HD;
    for (int i = t; i < NA * HD; i += 256) agl[i >> 5][i & 31] = agb[i];
    __syncthreads();
    int w = t >> 6, lane = t & 63;
    int n = nb + w;
    const float* qrow = q + ((b * NHD + h) * NN + n) * HD;
    float logit = -1e30f;
    if (lane < NA) {
        float acc = 0.f;
#pragma unroll
        for (int d = 0; d < HD; ++d) acc += qrow[d] * agl[lane][d];
        logit = acc * SCALE;
    }
    float mx = logit;
#pragma unroll
    for (int off = 32; off; off >>= 1) mx = fmaxf(mx, __shfl_xor(mx, off));
    float p = (lane < NA) ? __expf(logit - mx) : 0.f;
    float sum = p;
#pragma unroll
    for (int off = 32; off; off >>= 1) sum += __shfl_xor(sum, off);
    pl[w][lane] = p / sum;
    __syncthreads();
    if (lane < HD) {
        float acc = 0.f;
#pragma unroll
        for (int a = 0; a < NA; ++a) acc += pl[w][a] * agl[a][lane];
        qcs[((b * NHD + h) * NN + n) * HD + lane] = acc * SCALE;  // fold stage-2 scale
    }
}

// ---------------------------------------------------------------------------
// stage 2: flash attention. Br=32 q-rows/block, Bc=64 kv-cols/tile.
// S micro: each thread 2 rows x 4 cols; online-softmax state (m,l) lives in
// registers, replicated across each 16-lane row-group (rows never cross
// groups -> no LDS state, no extra barriers). K and V^T tiles XOR-swizzled
// (no pad) so the 4-row-stride b128 read pattern is conflict-free.
__global__ __launch_bounds__(256) void k_flash(const float* __restrict__ qc,
                                               const float* __restrict__ kg,
                                               const float* __restrict__ vg,
                                               float* __restrict__ ao) {
    __shared__ float Qs[32][36];
    __shared__ float Ks[64 * 32];   // swizzled: [r][ (kblk ^ ((r>>2)&7))*4 + e ]
    __shared__ float Vt[32 * 64];   // transposed+swizzled: [d][ (cblk ^ ((d>>1)&7))*4 + e ]
    __shared__ float Ps[32][68];
    int b = blockIdx.z, h = blockIdx.y;
    int n0 = blockIdx.x * 32;
    int t = threadIdx.x;
    int ty = t >> 4, tx = t & 15;
    const float* qb = qc + ((size_t)(b * NHD + h) * NN + n0) * HD;
    const float* kb = kg + (size_t)(b * NHD + h) * NN * HD;
    const float* vb = vg + (size_t)(b * NHD + h) * NN * HD;
    {   // load Q tile once: 32x32, 1 float4 per thread
        int r = t >> 3, d4 = (t & 7) * 4;
        *(float4*)&Qs[r][d4] = *(const float4*)&qb[r * HD + d4];
    }
    int r0 = ty * 2;          // S/PV rows owned by this thread
    int d0 = tx * 2;          // PV output cols
    float m0 = -1e30f, m1 = -1e30f, l0 = 0.f, l1 = 0.f;
    float o00 = 0.f, o01 = 0.f, o10 = 0.f, o11 = 0.f;

    for (int mt = 0; mt < NN / 64; ++mt) {
        __syncthreads();   // previous PV done before restaging
#pragma unroll
        for (int j = 0; j < 2; ++j) {   // K tile: 64 rows x 32, swizzled
            int idx = t + j * 256;
            int r = idx >> 3, kblk = idx & 7;
            int pk = kblk ^ ((r >> 2) & 7);
            *(float4*)&Ks[r * 32 + pk * 4] = *(const float4*)&kb[(mt * 64 + r) * HD + kblk * 4];
        }
#pragma unroll
        for (int j = 0; j < 2; ++j) {   // V tile transposed: Vt[d][c]
            int idx = t + j * 256;
            int c = idx >> 3, dblk = idx & 7;
            float4 vv = *(const float4*)&vb[(mt * 64 + c) * HD + dblk * 4];
            int cblk = c >> 2, cin = c & 3;
            float va[4] = {vv.x, vv.y, vv.z, vv.w};
#pragma unroll
            for (int e = 0; e < 4; ++e) {
                int d = dblk * 4 + e;
                Vt[d * 64 + ((cblk ^ ((d >> 1) & 7)) << 2) + cin] = va[e];
            }
        }
        __syncthreads();
        // ---- S = Qc_scaled @ K^T  (2 rows x 4 cols per thread)
        float s0[4] = {}, s1[4] = {};
#pragma unroll
        for (int kk = 0; kk < 8; ++kk) {
            float4 qa = *(float4*)&Qs[r0][kk * 4];
            float4 qbv = *(float4*)&Qs[r0 + 1][kk * 4];
#pragma unroll
            for (int j = 0; j < 4; ++j) {
                int r = tx * 4 + j;
                int pk = kk ^ ((r >> 2) & 7);
                float4 k4 = *(float4*)&Ks[r * 32 + pk * 4];
                s0[j] += qa.x * k4.x + qa.y * k4.y + qa.z * k4.z + qa.w * k4.w;
                s1[j] += qbv.x * k4.x + qbv.y * k4.y + qbv.z * k4.z + qbv.w * k4.w;
            }
        }
        // ---- online softmax (row stats across the 16-lane group)
        float tm0 = fmaxf(fmaxf(s0[0], s0[1]), fmaxf(s0[2], s0[3]));
        float tm1 = fmaxf(fmaxf(s1[0], s1[1]), fmaxf(s1[2], s1[3]));
#pragma unroll
        for (int off = 1; off < 16; off <<= 1) {
            tm0 = fmaxf(tm0, __shfl_xor(tm0, off));
            tm1 = fmaxf(tm1, __shfl_xor(tm1, off));
        }
        float mn0 = fmaxf(m0, tm0), mn1 = fmaxf(m1, tm1);
        float al0 = __expf(m0 - mn0), al1 = __expf(m1 - mn1);
        float ps0 = 0.f, ps1 = 0.f;
#pragma unroll
        for (int j = 0; j < 4; ++j) {
            s0[j] = __expf(s0[j] - mn0); ps0 += s0[j];
            s1[j] = __expf(s1[j] - mn1); ps1 += s1[j];
        }
#pragma unroll
        for (int off = 1; off < 16; off <<= 1) {
            ps0 += __shfl_xor(ps0, off);
            ps1 += __shfl_xor(ps1, off);
        }
        l0 = l0 * al0 + ps0; l1 = l1 * al1 + ps1;
        m0 = mn0; m1 = mn1;
        *(float4*)&Ps[r0][tx * 4]     = make_float4(s0[0], s0[1], s0[2], s0[3]);
        *(float4*)&Ps[r0 + 1][tx * 4] = make_float4(s1[0], s1[1], s1[2], s1[3]);
        o00 *= al0; o01 *= al0; o10 *= al1; o11 *= al1;
        __syncthreads();
        // ---- O += P @ V  (2 rows x 2 cols per thread)
        int sw = (d0 >> 1) & 7;   // same swizzle for d0 and d0+1 (d0 even)
#pragma unroll
        for (int cb = 0; cb < 16; ++cb) {
            float4 p0 = *(float4*)&Ps[r0][cb * 4];
            float4 p1 = *(float4*)&Ps[r0 + 1][cb * 4];
            float4 v0 = *(float4*)&Vt[d0 * 64 + ((cb ^ sw) << 2)];
            float4 v1 = *(float4*)&Vt[(d0 + 1) * 64 + ((cb ^ sw) << 2)];
            o00 += p0.x * v0.x + p0.y * v0.y + p0.z * v0.z + p0.w * v0.w;
            o01 += p0.x * v1.x + p0.y * v1.y + p0.z * v1.z + p0.w * v1.w;
            o10 += p1.x * v0.x + p1.y * v0.y + p1.z * v0.z + p1.w * v0.w;
            o11 += p1.x * v1.x + p1.y * v1.y + p1.z * v1.z + p1.w * v1.w;
        }
    }
    float inv0 = 1.f / l0, inv1 = 1.f / l1;
    size_t base0 = ((size_t)(b * NN + n0 + r0)) * NC + h * HD + d0;
    size_t base1 = ((size_t)(b * NN + n0 + r0 + 1)) * NC + h * HD + d0;
    ao[base0]     = o00 * inv0;
    ao[base0 + 1] = o01 * inv0;
    ao[base1]     = o10 * inv1;
    ao[base1 + 1] = o11 * inv1;
}

// ---------------------------------------------------------------------------
__global__ void k_transpose_wp(const float* __restrict__ wp, float* __restrict__ wpt) {
    int idx = blockIdx.x * 256 + threadIdx.x;
    if (idx >= NC * NC) return;
    int o = idx / NC, c = idx % NC;
    wpt[c * NC + o] = wp[idx];
}

// proj + LayerNorm + final [B,N,C] -> [B,C,H,W] transpose. 1 block per (b,n).
__global__ __launch_bounds__(128) void k_proj_ln(const float* __restrict__ ao,
                                                 const float* __restrict__ wpt,
                                                 const float* __restrict__ bp,
                                                 const float* __restrict__ g,
                                                 const float* __restrict__ bb,
                                                 void* __restrict__ out,
                                                 const int* __restrict__ flag) {
    __shared__ float row[NC];
    __shared__ float red[4];
    int bn = blockIdx.x;              // b*NN + n
    int b = bn / NN, n = bn % NN;
    int o = threadIdx.x;
    row[o] = ao[(size_t)bn * NC + o];
    __syncthreads();
    float acc = bp[o];
#pragma unroll 8
    for (int c = 0; c < NC; ++c) acc += row[c] * wpt[c * NC + o];   // coalesced
    float s1 = acc, s2 = acc * acc;
#pragma unroll
    for (int off = 32; off; off >>= 1) {
        s1 += __shfl_xor(s1, off);
        s2 += __shfl_xor(s2, off);
    }
    if ((o & 63) == 0) { red[(o >> 6) * 2] = s1; red[(o >> 6) * 2 + 1] = s2; }
    __syncthreads();
    float mu  = (red[0] + red[2]) * (1.f / NC);
    float ex2 = (red[1] + red[3]) * (1.f / NC);
    float rstd = rsqrtf(ex2 - mu * mu + 1e-5f);
    float val = (acc - mu) * rstd * g[o] + bb[o];
    size_t oidx = ((size_t)(b * NC + o)) * NN + n;
    if (*flag) ((__hip_bfloat16*)out)[oidx] = __float2bfloat16(val);
    else       ((float*)out)[oidx] = val;
}

// ---------------------------------------------------------------------------
extern "C" void kernel_launch(void* const* d_in, const int* in_sizes, int n_in,
                              void* d_out, int out_size, void* d_ws, size_t ws_size,
                              hipStream_t stream) {
    const void* x_raw  = d_in[0];
    const void* wq_raw = d_in[1];
    const void* wp_raw = d_in[2];
    const void* bp_raw = d_in[3];
    const void* lg_raw = d_in[4];
    const void* lb_raw = d_in[5];

    float* ws   = (float*)d_ws;
    int*   flag = (int*)d_ws;
    float* xf    = ws + 16;
    float* wqkv  = xf + NB * NC * NN;        // 802816
    float* wproj = wqkv + 3 * NC * NC;       // 49152
    float* wpt   = wproj + NC * NC;
    float* bproj = wpt + NC * NC;
    float* lng   = bproj + NC;
    float* lnb   = lng + NC;
    float* q     = lnb + NC;
    float* k     = q + NB * NHD * NN * HD;
    float* v     = k + NB * NHD * NN * HD;
    float* ag    = v + NB * NHD * NN * HD;
    float* qcs   = ag + NB * NHD * NA * HD;
    float* ao    = qcs + NB * NHD * NN * HD;
    // total ~4.94M floats ~19.8 MB

    k_detect<<<1, 256, 0, stream>>>((const u16*)x_raw, flag);

    const void* srcs[6] = {x_raw, wq_raw, wp_raw, bp_raw, lg_raw, lb_raw};
    float* dsts[6] = {xf, wqkv, wproj, bproj, lng, lnb};
    int ns[6] = {NB * NC * NN, 3 * NC * NC, NC * NC, NC, NC, NC};
    for (int i = 0; i < 6; ++i)
        k_convert<<<(ns[i] + 255) / 256, 256, 0, stream>>>(srcs[i], dsts[i], ns[i], flag);

    k_qkv<<<dim3(NN / 64, 6, NB), 256, 0, stream>>>(xf, wqkv, q, k, v);
    k_agent<<<(NB * NC * NA + 255) / 256, 256, 0, stream>>>(xf, ag);
    k_stage1<<<dim3(NN / 4, NHD, NB), 256, 0, stream>>>(q, ag, qcs);
    k_flash<<<dim3(NN / 32, NHD, NB), 256, 0, stream>>>(qcs, k, v, ao);
    k_transpose_wp<<<(NC * NC + 255) / 256, 256, 0, stream>>>(wproj, wpt);
    k_proj_ln<<<NB * NN, 128, 0, stream>>>(ao, wpt, bproj, lng, lnb, d_out, flag);
}

// Round 2
// 227.789 us; speedup vs baseline: 2.4835x; 2.4835x over previous
//
#include <hip/hip_runtime.h>
#include <hip/hip_bf16.h>
#include <stdint.h>

typedef unsigned short u16;
typedef __attribute__((ext_vector_type(8))) short short8;   // 8 bf16 (4 VGPRs)
typedef __attribute__((ext_vector_type(4))) float f32x4;    // MFMA C/D

#define NB 2
#define NC 128
#define NHD 4      // heads
#define HD 32      // head dim
#define NN 3136    // H*W
#define NA 49      // agent tokens
#define SCALE 0.17677669529663687f  // 1/sqrt(32)
#define LOG2E 1.4426950408889634f

__device__ inline u16 bfb(float f) {
    __hip_bfloat16 h = __float2bfloat16(f);
    return *(u16*)&h;
}

// ---------------------------------------------------------------------------
// dtype detection (bf16 vs fp32 inputs) — see round 0.
__global__ void k_detect(const u16* __restrict__ raw, int* __restrict__ flag) {
    __shared__ int cnt;
    if (threadIdx.x == 0) cnt = 0;
    __syncthreads();
    u16 w = raw[threadIdx.x * 97];
    float f = __uint_as_float(((uint32_t)w) << 16);
    float a = fabsf(f);
    if (a >= 1e-4f && a <= 100.0f) atomicAdd(&cnt, 1);
    __syncthreads();
    if (threadIdx.x == 0) *flag = (cnt >= 230) ? 1 : 0;
}

__global__ void k_convert(const void* __restrict__ src, float* __restrict__ dst,
                          int n, const int* __restrict__ flag) {
    int i = blockIdx.x * 256 + threadIdx.x;
    if (i >= n) return;
    if (*flag) {
        u16 w = ((const u16*)src)[i];
        dst[i] = __uint_as_float(((uint32_t)w) << 16);
    } else {
        dst[i] = ((const float*)src)[i];
    }
}

// ---------------------------------------------------------------------------
// QKV: per batch GEMM [384x128] @ [128x3136]. 64x64 tile, 4x4 micro-tile.
// q -> fp32 [b,h,n,d]; k -> bf16 [b,h,n,d]; v -> bf16 TRANSPOSED [b,h,d,n].
__global__ __launch_bounds__(256) void k_qkv(const float* __restrict__ xf,
                                             const float* __restrict__ wf,
                                             float* __restrict__ q,
                                             u16* __restrict__ kbf,
                                             u16* __restrict__ vtb) {
    __shared__ float wl[64][36];
    __shared__ float xl[32][68];
    int b  = blockIdx.z;
    int o0 = blockIdx.y * 64;
    int n0 = blockIdx.x * 64;
    int t  = threadIdx.x;
    int ty = t >> 4, tx = t & 15;
    float acc[4][4] = {};
    for (int kk = 0; kk < 4; ++kk) {
        __syncthreads();
#pragma unroll
        for (int j = 0; j < 2; ++j) {
            int idx = t + j * 256;
            int r = idx >> 3, c4 = (idx & 7) * 4;
            *(float4*)&wl[r][c4] = *(const float4*)&wf[(o0 + r) * NC + kk * 32 + c4];
        }
#pragma unroll
        for (int j = 0; j < 2; ++j) {
            int idx = t + j * 256;
            int r = idx >> 4, c4 = (idx & 15) * 4;
            *(float4*)&xl[r][c4] = *(const float4*)&xf[(b * NC + kk * 32 + r) * NN + n0 + c4];
        }
        __syncthreads();
#pragma unroll
        for (int c = 0; c < 32; ++c) {
            float a0 = wl[ty * 4 + 0][c], a1 = wl[ty * 4 + 1][c];
            float a2 = wl[ty * 4 + 2][c], a3 = wl[ty * 4 + 3][c];
            float4 b4 = *(float4*)&xl[c][tx * 4];
            acc[0][0] += a0 * b4.x; acc[0][1] += a0 * b4.y; acc[0][2] += a0 * b4.z; acc[0][3] += a0 * b4.w;
            acc[1][0] += a1 * b4.x; acc[1][1] += a1 * b4.y; acc[1][2] += a1 * b4.z; acc[1][3] += a1 * b4.w;
            acc[2][0] += a2 * b4.x; acc[2][1] += a2 * b4.y; acc[2][2] += a2 * b4.z; acc[2][3] += a2 * b4.w;
            acc[3][0] += a3 * b4.x; acc[3][1] += a3 * b4.y; acc[3][2] += a3 * b4.z; acc[3][3] += a3 * b4.w;
        }
    }
    int ob = o0 + ty * 4;
    int tq = ob >> 7, h = (ob >> 5) & 3, d0 = ob & 31;
    size_t bh = (size_t)b * NHD + h;
    if (tq == 0) {
#pragma unroll
        for (int j = 0; j < 4; ++j) {
            int n = n0 + tx * 4 + j;
            float4 val = make_float4(acc[0][j], acc[1][j], acc[2][j], acc[3][j]);
            *(float4*)&q[(bh * NN + n) * HD + d0] = val;
        }
    } else if (tq == 1) {
#pragma unroll
        for (int j = 0; j < 4; ++j) {
            int n = n0 + tx * 4 + j;
            ushort4 w = make_ushort4(bfb(acc[0][j]), bfb(acc[1][j]),
                                     bfb(acc[2][j]), bfb(acc[3][j]));
            *(ushort4*)&kbf[(bh * NN + n) * HD + d0] = w;
        }
    } else {
#pragma unroll
        for (int i = 0; i < 4; ++i) {
            ushort4 w = make_ushort4(bfb(acc[i][0]), bfb(acc[i][1]),
                                     bfb(acc[i][2]), bfb(acc[i][3]));
            *(ushort4*)&vtb[(bh * HD + d0 + i) * NN + n0 + tx * 4] = w;
        }
    }
}

// ---------------------------------------------------------------------------
// agent tokens: 8x8 block mean of x -> [b][h][a][d]
__global__ void k_agent(const float* __restrict__ xf, float* __restrict__ ag) {
    int idx = blockIdx.x * 256 + threadIdx.x;
    if (idx >= NB * NC * NA) return;
    int b = idx / (NC * NA);
    int r = idx % (NC * NA);
    int c = r / NA;
    int a = r % NA;
    int ai = a / 7, aj = a % 7;
    const float* base = xf + (b * NC + c) * NN + ai * 8 * 56 + aj * 8;
    float s = 0.f;
#pragma unroll
    for (int u = 0; u < 8; ++u) {
        float4 v0 = *(const float4*)&base[u * 56];
        float4 v1 = *(const float4*)&base[u * 56 + 4];
        s += v0.x + v0.y + v0.z + v0.w + v1.x + v1.y + v1.z + v1.w;
    }
    int h = c >> 5, d = c & 31;
    ag[((b * NHD + h) * NA + a) * HD + d] = s * (1.f / 64.f);
}

// ---------------------------------------------------------------------------
// stage 1: per q-row softmax over 49 agents -> q_compressed, stored bf16
// pre-scaled by SCALE*LOG2E (stage-2 scale folded, exp2-ready).
__global__ __launch_bounds__(256) void k_stage1(const float* __restrict__ q,
                                                const float* __restrict__ ag,
                                                u16* __restrict__ qcb) {
    __shared__ float agl[NA][33];
    __shared__ float pl[4][64];
    int b = blockIdx.z, h = blockIdx.y;
    int nb = blockIdx.x * 4;
    int t = threadIdx.x;
    const float* agb = ag + (b * NHD + h) * NA * HD;
    for (int i = t; i < NA * HD; i += 256) agl[i >> 5][i & 31] = agb[i];
    __syncthreads();
    int w = t >> 6, lane = t & 63;
    int n = nb + w;
    const float* qrow = q + ((b * NHD + h) * NN + n) * HD;
    float logit = -1e30f;
    if (lane < NA) {
        float acc = 0.f;
#pragma unroll
        for (int d = 0; d < HD; ++d) acc += qrow[d] * agl[lane][d];
        logit = acc * SCALE;
    }
    float mx = logit;
#pragma unroll
    for (int off = 32; off; off >>= 1) mx = fmaxf(mx, __shfl_xor(mx, off));
    float p = (lane < NA) ? __expf(logit - mx) : 0.f;
    float sum = p;
#pragma unroll
    for (int off = 32; off; off >>= 1) sum += __shfl_xor(sum, off);
    pl[w][lane] = p / sum;
    __syncthreads();
    if (lane < HD) {
        float acc = 0.f;
#pragma unroll
        for (int a = 0; a < NA; ++a) acc += pl[w][a] * agl[a][lane];
        qcb[((size_t)(b * NHD + h) * NN + n) * HD + lane] = bfb(acc * (SCALE * LOG2E));
    }
}

// ---------------------------------------------------------------------------
// stage 2: MFMA flash. One wave = 16 q-rows; 32 keys/iter as 2 subtiles
// (even/odd keys so exp results pack into b32 LDS writes). No online max:
// P = exp2(s) unnormalized, l accumulated via a 3rd MFMA with B=ones (lands
// in the same C layout as O -> per-lane normalize, zero shuffles). P transpose
// C->A layout via wave-private LDS (no __syncthreads anywhere). K split 2-way
// across blocks; partials combined in k_proj_ln.
__global__ __launch_bounds__(256) void k_flash_mfma(const u16* __restrict__ qc,
                                                    const u16* __restrict__ kb,
                                                    const u16* __restrict__ vt,
                                                    float* __restrict__ op,
                                                    float* __restrict__ lp) {
    __shared__ u16 Pbuf[4][16 * 40];   // per-wave, stride 40 (80B rows, 16B-aligned)
    int b = blockIdx.z;
    int h = blockIdx.y & 3;
    int s = blockIdx.y >> 2;
    int wave = threadIdx.x >> 6, lane = threadIdx.x & 63;
    int c = lane & 15, u = lane >> 4;   // frag col / quad
    int q0 = blockIdx.x * 64 + wave * 16;
    size_t bh = (size_t)b * NHD + h;
    const u16* kbase = kb + bh * NN * HD;
    const u16* vbase = vt + bh * HD * NN;
    // A frag (held all loop): Q[m=c][k=u*8+j]
    short8 qfrag = *(const short8*)(qc + (bh * NN + q0 + c) * HD + u * 8);
    short8 ones;
#pragma unroll
    for (int i = 0; i < 8; ++i) ones[i] = (short)0x3F80;   // bf16 1.0
    f32x4 o0 = {0.f, 0.f, 0.f, 0.f};
    f32x4 o1 = {0.f, 0.f, 0.f, 0.f};
    f32x4 lacc = {0.f, 0.f, 0.f, 0.f};
    const f32x4 z = {0.f, 0.f, 0.f, 0.f};
    u16* pw = &Pbuf[wave][0];
    int k0 = s * (NN / 2);
#pragma unroll 2
    for (int kt = 0; kt < NN / 2; kt += 32) {
        int kk = k0 + kt;
        // B frags: subtile 0 = even keys kk+2c, subtile 1 = odd keys kk+2c+1
        short8 kf0 = *(const short8*)(kbase + (size_t)(kk + 2 * c) * HD + u * 8);
        short8 kf1 = *(const short8*)(kbase + (size_t)(kk + 2 * c + 1) * HD + u * 8);
        // V^T frags: rows d=c and d=16+c, keys kk+u*8..+7
        short8 vf0 = *(const short8*)(vbase + (size_t)c * NN + kk + u * 8);
        short8 vf1 = *(const short8*)(vbase + (size_t)(c + 16) * NN + kk + u * 8);
        f32x4 sc0 = __builtin_amdgcn_mfma_f32_16x16x32_bf16(qfrag, kf0, z, 0, 0, 0);
        f32x4 sc1 = __builtin_amdgcn_mfma_f32_16x16x32_bf16(qfrag, kf1, z, 0, 0, 0);
#pragma unroll
        for (int r = 0; r < 4; ++r) {
            // C layout: row = u*4+r, keys 2c (sub0) / 2c+1 (sub1) -> adjacent
            float p0 = __builtin_amdgcn_exp2f(sc0[r]);
            float p1 = __builtin_amdgcn_exp2f(sc1[r]);
            __hip_bfloat162 pk2 = __float22bfloat162_rn(make_float2(p0, p1));
            *(uint32_t*)(pw + (u * 4 + r) * 40 + 2 * c) = *(uint32_t*)&pk2;
        }
        // A frag of P: row c, keys u*8+j (natural key order in LDS)
        short8 pf = *(const short8*)(pw + c * 40 + u * 8);
        o0 = __builtin_amdgcn_mfma_f32_16x16x32_bf16(pf, vf0, o0, 0, 0, 0);
        o1 = __builtin_amdgcn_mfma_f32_16x16x32_bf16(pf, vf1, o1, 0, 0, 0);
        lacc = __builtin_amdgcn_mfma_f32_16x16x32_bf16(pf, ones, lacc, 0, 0, 0);
    }
    // O partial (unnormalized) -> op[s][b][n][c], l -> lp[s][b][h][n]
    float* obase = op + ((size_t)(s * NB + b) * NN + q0) * NC + h * HD;
#pragma unroll
    for (int r = 0; r < 4; ++r) {
        int row = u * 4 + r;
        obase[(size_t)row * NC + c]      = o0[r];
        obase[(size_t)row * NC + 16 + c] = o1[r];
    }
    if (c == 0) {
        float* lbase = lp + ((size_t)(s * NB * NHD) + bh) * NN + q0;
#pragma unroll
        for (int r = 0; r < 4; ++r) lbase[u * 4 + r] = lacc[r];
    }
}

// ---------------------------------------------------------------------------
__global__ void k_transpose_wp(const float* __restrict__ wp, float* __restrict__ wpt) {
    int idx = blockIdx.x * 256 + threadIdx.x;
    if (idx >= NC * NC) return;
    int o = idx / NC, c = idx % NC;
    wpt[c * NC + o] = wp[idx];
}

// combine K-split partials + normalize + proj + LayerNorm + NCHW transpose.
__global__ __launch_bounds__(128) void k_proj_ln(const float* __restrict__ op,
                                                 const float* __restrict__ lp,
                                                 const float* __restrict__ wpt,
                                                 const float* __restrict__ bp,
                                                 const float* __restrict__ g,
                                                 const float* __restrict__ bb,
                                                 void* __restrict__ out,
                                                 const int* __restrict__ flag) {
    __shared__ float row[NC];
    __shared__ float red[4];
    int bn = blockIdx.x;
    int b = bn / NN, n = bn % NN;
    int o = threadIdx.x;
    int h = o >> 5;
    size_t lidx = ((size_t)(b * NHD + h)) * NN + n;
    float lsum = lp[lidx] + lp[(size_t)(NB * NHD) * NN + lidx];
    float oval = op[(size_t)bn * NC + o] + op[(size_t)(NB * NN) * NC + (size_t)bn * NC + o];
    row[o] = oval / lsum;
    __syncthreads();
    float acc = bp[o];
#pragma unroll 8
    for (int c = 0; c < NC; ++c) acc += row[c] * wpt[c * NC + o];
    float s1 = acc, s2 = acc * acc;
#pragma unroll
    for (int off = 32; off; off >>= 1) {
        s1 += __shfl_xor(s1, off);
        s2 += __shfl_xor(s2, off);
    }
    if ((o & 63) == 0) { red[(o >> 6) * 2] = s1; red[(o >> 6) * 2 + 1] = s2; }
    __syncthreads();
    float mu  = (red[0] + red[2]) * (1.f / NC);
    float ex2 = (red[1] + red[3]) * (1.f / NC);
    float rstd = rsqrtf(ex2 - mu * mu + 1e-5f);
    float val = (acc - mu) * rstd * g[o] + bb[o];
    size_t oidx = ((size_t)(b * NC + o)) * NN + n;
    if (*flag) ((__hip_bfloat16*)out)[oidx] = __float2bfloat16(val);
    else       ((float*)out)[oidx] = val;
}

// ---------------------------------------------------------------------------
extern "C" void kernel_launch(void* const* d_in, const int* in_sizes, int n_in,
                              void* d_out, int out_size, void* d_ws, size_t ws_size,
                              hipStream_t stream) {
    const void* x_raw  = d_in[0];
    const void* wq_raw = d_in[1];
    const void* wp_raw = d_in[2];
    const void* bp_raw = d_in[3];
    const void* lg_raw = d_in[4];
    const void* lb_raw = d_in[5];

    float* ws   = (float*)d_ws;
    int*   flag = (int*)d_ws;
    float* xf    = ws + 16;
    float* wqkv  = xf + NB * NC * NN;
    float* wproj = wqkv + 3 * NC * NC;
    float* wpt   = wproj + NC * NC;
    float* bproj = wpt + NC * NC;
    float* lng   = bproj + NC;
    float* lnb   = lng + NC;
    float* q     = lnb + NC;                       // fp32 [b,h,n,d]
    u16*   kbf   = (u16*)(q + NB * NHD * NN * HD); // bf16 [b,h,n,d]
    u16*   vtb   = kbf + NB * NHD * NN * HD;       // bf16 [b,h,d,n]
    u16*   qcb   = vtb + NB * NHD * NN * HD;       // bf16 [b,h,n,d] prescaled
    float* ag    = (float*)(qcb + NB * NHD * NN * HD);
    float* op    = ag + NB * NHD * NA * HD;        // [2][b][n][128] partial O
    float* lp    = op + 2 * NB * NN * NC;          // [2][b][h][n]   partial l
    // total ~4.56M floats ~18.2 MB

    k_detect<<<1, 256, 0, stream>>>((const u16*)x_raw, flag);

    const void* srcs[6] = {x_raw, wq_raw, wp_raw, bp_raw, lg_raw, lb_raw};
    float* dsts[6] = {xf, wqkv, wproj, bproj, lng, lnb};
    int ns[6] = {NB * NC * NN, 3 * NC * NC, NC * NC, NC, NC, NC};
    for (int i = 0; i < 6; ++i)
        k_convert<<<(ns[i] + 255) / 256, 256, 0, stream>>>(srcs[i], dsts[i], ns[i], flag);

    k_qkv<<<dim3(NN / 64, 6, NB), 256, 0, stream>>>(xf, wqkv, q, kbf, vtb);
    k_agent<<<(NB * NC * NA + 255) / 256, 256, 0, stream>>>(xf, ag);
    k_stage1<<<dim3(NN / 4, NHD, NB), 256, 0, stream>>>(q, ag, qcb);
    k_flash_mfma<<<dim3(NN / 64, NHD * 2, NB), 256, 0, stream>>>(qcb, kbf, vtb, op, lp);
    k_transpose_wp<<<(NC * NC + 255) / 256, 256, 0, stream>>>(wproj, wpt);
    k_proj_ln<<<NB * NN, 128, 0, stream>>>(op, lp, wpt, bproj, lng, lnb, d_out, flag);
}

// Round 3
// 211.973 us; speedup vs baseline: 2.6688x; 1.0746x over previous
//
#include <hip/hip_runtime.h>
#include <hip/hip_bf16.h>
#include <stdint.h>

typedef unsigned short u16;
typedef __attribute__((ext_vector_type(8))) short short8;   // 8 bf16 (4 VGPRs)
typedef __attribute__((ext_vector_type(4))) short short4v;  // 4 bf16 (2 VGPRs)
typedef __attribute__((ext_vector_type(4))) float f32x4;    // MFMA C/D

#define NB 2
#define NC 128
#define NHD 4      // heads
#define HD 32      // head dim
#define NN 3136    // H*W
#define NA 49      // agent tokens
#define NSPLIT 4   // flash K-split
#define SCALE 0.17677669529663687f  // 1/sqrt(32)
#define LOG2E 1.4426950408889634f
#define QSC (SCALE * LOG2E)

__device__ inline u16 bfb(float f) {
    __hip_bfloat16 h = __float2bfloat16(f);
    return *(u16*)&h;
}
__device__ inline float b2f(u16 w) {
    return __uint_as_float(((uint32_t)w) << 16);
}
// pack 4 floats -> 4 bf16 (j-order: [0]=low of dword0)
__device__ inline short4v pack4(float a, float b, float c, float d) {
    union { short4v s; __hip_bfloat162 h[2]; } u;
    u.h[0] = __float22bfloat162_rn(make_float2(a, b));
    u.h[1] = __float22bfloat162_rn(make_float2(c, d));
    return u.s;
}
__device__ inline float ldf(const void* p, size_t i, int f) {
    return f ? b2f(((const u16*)p)[i]) : ((const float*)p)[i];
}

// ---------------------------------------------------------------------------
// dtype detection (bf16 vs fp32 inputs)
__global__ void k_detect(const u16* __restrict__ raw, int* __restrict__ flag) {
    __shared__ int cnt;
    if (threadIdx.x == 0) cnt = 0;
    __syncthreads();
    u16 w = raw[threadIdx.x * 97];
    float f = b2f(w);
    float a = fabsf(f);
    if (a >= 1e-4f && a <= 100.0f) atomicAdd(&cnt, 1);
    __syncthreads();
    if (threadIdx.x == 0) *flag = (cnt >= 230) ? 1 : 0;
}

// ---------------------------------------------------------------------------
// x convert: xf fp32 [b][c][n] (for agent pool) + xT bf16 [b][n][c] (for QKV
// MFMA B-frags). Tile transpose through LDS. grid (196, NB), block 256.
__global__ __launch_bounds__(256) void k_conv_x(const void* __restrict__ xr,
                                                float* __restrict__ xf,
                                                u16* __restrict__ xT,
                                                const int* __restrict__ flag) {
    __shared__ u16 tile[128][18];
    int b = blockIdx.y;
    int n0 = blockIdx.x * 16;
    int t = threadIdx.x;
    int f = *flag;
    int c = t >> 1, nh = (t & 1) * 8;
    size_t src = ((size_t)(b * 128 + c)) * NN + n0 + nh;
    float a[8];
#pragma unroll
    for (int i = 0; i < 8; ++i) a[i] = ldf(xr, src + i, f);
#pragma unroll
    for (int i = 0; i < 8; ++i) xf[src + i] = a[i];
#pragma unroll
    for (int i = 0; i < 8; ++i) tile[c][nh + i] = bfb(a[i]);
    __syncthreads();
    int n = t >> 4, c0 = (t & 15) * 8;
    short8 o;
#pragma unroll
    for (int i = 0; i < 8; ++i) o[i] = (short)tile[c0 + i][n];
    *(short8*)&xT[((size_t)b * NN + n0 + n) * 128 + c0] = o;
}

// ---------------------------------------------------------------------------
// weight convert: wbf bf16 (384x128), wpt fp32 transposed [c][o], biases.
// grid 258 blocks x 256.
__global__ void k_conv_w(const void* __restrict__ wq, const void* __restrict__ wp,
                         const void* __restrict__ bp, const void* __restrict__ g,
                         const void* __restrict__ bb,
                         u16* __restrict__ wbf, float* __restrict__ wpt,
                         float* __restrict__ bgb, const int* __restrict__ flag) {
    int bx = blockIdx.x, t = threadIdx.x;
    int f = *flag;
    if (bx < 192) {
        int i = bx * 256 + t;
        wbf[i] = bfb(ldf(wq, i, f));
    } else if (bx < 256) {
        int i = (bx - 192) * 256 + t;
        wpt[(i & 127) * 128 + (i >> 7)] = ldf(wp, i, f);
    } else {
        int i = (bx - 256) * 256 + t;
        if (i < 128)      bgb[i] = ldf(bp, i, f);
        else if (i < 256) bgb[i] = ldf(g, i - 128, f);
        else if (i < 384) bgb[i] = ldf(bb, i - 256, f);
    }
}

// ---------------------------------------------------------------------------
// QKV via bf16 MFMA: [384x128] @ [128xN]. Each wave: 16 o x 64 n, K=128 in
// 4 frags. q bf16 [b,h,n,d] PRESCALED by SCALE*LOG2E (only stage1 reads it);
// k bf16 [b,h,n,d]; v bf16 TRANSPOSED [b,h,d,n]. grid (49, 6, NB) x 256.
__global__ __launch_bounds__(256) void k_qkv2(const u16* __restrict__ xT,
                                              const u16* __restrict__ wbf,
                                              u16* __restrict__ qb,
                                              u16* __restrict__ kbf,
                                              u16* __restrict__ vtb) {
    int b = blockIdx.z;
    int n0 = blockIdx.x * 64;
    int w = threadIdx.x >> 6, lane = threadIdx.x & 63;
    int c = lane & 15, u = lane >> 4;
    int o0 = blockIdx.y * 64 + w * 16;
    const f32x4 z = {0.f, 0.f, 0.f, 0.f};
    short8 af[4];
#pragma unroll
    for (int kt = 0; kt < 4; ++kt)
        af[kt] = *(const short8*)&wbf[(o0 + c) * 128 + kt * 32 + u * 8];
    int tq = o0 >> 7, h = (o0 >> 5) & 3, d0 = (o0 & 31) + u * 4;
    size_t bh = (size_t)b * NHD + h;
#pragma unroll
    for (int nt = 0; nt < 4; ++nt) {
        int n = n0 + nt * 16 + c;
        f32x4 acc = z;
#pragma unroll
        for (int kt = 0; kt < 4; ++kt) {
            short8 bfr = *(const short8*)&xT[((size_t)b * NN + n) * 128 + kt * 32 + u * 8];
            acc = __builtin_amdgcn_mfma_f32_16x16x32_bf16(af[kt], bfr, acc, 0, 0, 0);
        }
        if (tq == 0) {
            *(short4v*)&qb[(bh * NN + n) * HD + d0] =
                pack4(acc[0] * QSC, acc[1] * QSC, acc[2] * QSC, acc[3] * QSC);
        } else if (tq == 1) {
            *(short4v*)&kbf[(bh * NN + n) * HD + d0] =
                pack4(acc[0], acc[1], acc[2], acc[3]);
        } else {
#pragma unroll
            for (int r = 0; r < 4; ++r)
                vtb[(bh * HD + d0 + r) * NN + n] = bfb(acc[r]);
        }
    }
}

// ---------------------------------------------------------------------------
// agent tokens: 8x8 block mean -> agb bf16 [b,h][64(pad)][32] and
// agTb bf16 [b,h][32][64(pad)], pads zeroed. grid 79 x 256.
__global__ void k_agent(const float* __restrict__ xf, u16* __restrict__ agb,
                        u16* __restrict__ agT) {
    int idx = blockIdx.x * 256 + threadIdx.x;
    const int NPOOL = NB * NC * NA;   // 12544
    if (idx < NPOOL) {
        int b = idx / (NC * NA);
        int r = idx % (NC * NA);
        int c = r / NA;
        int a = r % NA;
        int ai = a / 7, aj = a % 7;
        const float* base = xf + (b * NC + c) * NN + ai * 8 * 56 + aj * 8;
        float s = 0.f;
#pragma unroll
        for (int uu = 0; uu < 8; ++uu) {
            float4 v0 = *(const float4*)&base[uu * 56];
            float4 v1 = *(const float4*)&base[uu * 56 + 4];
            s += v0.x + v0.y + v0.z + v0.w + v1.x + v1.y + v1.z + v1.w;
        }
        int h = c >> 5, d = c & 31;
        int bh = b * NHD + h;
        u16 val = bfb(s * (1.f / 64.f));
        agb[bh * 2048 + a * 32 + d] = val;
        agT[bh * 2048 + d * 64 + a] = val;
    } else {
        int j = idx - NPOOL;
        if (j < 3840) {            // agb pad rows 49..63
            int bh = j / 480, rem = j % 480;
            int a = 49 + rem / 32, d = rem % 32;
            agb[bh * 2048 + a * 32 + d] = 0;
        } else if (j < 7680) {     // agT pad cols 49..63
            j -= 3840;
            int bh = j / 480, rem = j % 480;
            int a = 49 + rem / 32, d = rem % 32;
            agT[bh * 2048 + d * 64 + a] = 0;
        }
    }
}

// ---------------------------------------------------------------------------
// stage 1 via MFMA. S^T = Ag·Q^T (4 m-tiles, agents padded to 64); C-frag of
// S^T == B-operand layout of 16x16x16 MFMA, so normalized P feeds qc^T = 
// Ag^T·P^T directly. qcb bf16 prescaled by SCALE*LOG2E. grid (49,4,NB) x 256.
__global__ __launch_bounds__(256) void k_stage1_2(const u16* __restrict__ qb,
                                                  const u16* __restrict__ agb,
                                                  const u16* __restrict__ agT,
                                                  u16* __restrict__ qcb) {
    int b = blockIdx.z, h = blockIdx.y;
    int w = threadIdx.x >> 6, lane = threadIdx.x & 63;
    int c = lane & 15, u = lane >> 4;
    int q0 = blockIdx.x * 64 + w * 16;
    size_t bh = (size_t)b * NHD + h;
    const u16* aB = agb + bh * 2048;
    const u16* aT = agT + bh * 2048;
    const f32x4 z = {0.f, 0.f, 0.f, 0.f};
    short8 qf = *(const short8*)&qb[(bh * NN + q0 + c) * HD + u * 8];
    f32x4 st[4];
#pragma unroll
    for (int t = 0; t < 4; ++t) {
        short8 afr = *(const short8*)&aB[(t * 16 + c) * 32 + u * 8];
        st[t] = __builtin_amdgcn_mfma_f32_16x16x32_bf16(afr, qf, z, 0, 0, 0);
    }
    float e[4][4];
    float lsum = 0.f;
#pragma unroll
    for (int t = 0; t < 4; ++t)
#pragma unroll
        for (int r = 0; r < 4; ++r) {
            float v = __builtin_amdgcn_exp2f(st[t][r]);
            if (t == 3 && !(u == 0 && r == 0)) v = 0.f;   // agents >= 49
            e[t][r] = v;
            lsum += v;
        }
    lsum += __shfl_xor(lsum, 16);
    lsum += __shfl_xor(lsum, 32);
    float linv = 1.f / lsum;
    f32x4 qlo = z, qhi = z;
#pragma unroll
    for (int t = 0; t < 4; ++t) {
        short4v pf = pack4(e[t][0] * linv, e[t][1] * linv, e[t][2] * linv, e[t][3] * linv);
        short4v alo = *(const short4v*)&aT[c * 64 + t * 16 + u * 4];
        short4v ahi = *(const short4v*)&aT[(c + 16) * 64 + t * 16 + u * 4];
        qlo = __builtin_amdgcn_mfma_f32_16x16x16bf16_1k(alo, pf, qlo, 0, 0, 0);
        qhi = __builtin_amdgcn_mfma_f32_16x16x16bf16_1k(ahi, pf, qhi, 0, 0, 0);
    }
    u16* dst = &qcb[(bh * NN + q0 + c) * HD];
    *(short4v*)&dst[u * 4]      = pack4(qlo[0] * QSC, qlo[1] * QSC, qlo[2] * QSC, qlo[3] * QSC);
    *(short4v*)&dst[16 + u * 4] = pack4(qhi[0] * QSC, qhi[1] * QSC, qhi[2] * QSC, qhi[3] * QSC);
}

// ---------------------------------------------------------------------------
// stage 2 flash, zero-LDS. Per 32-key tile: S^T = K·Q^T (2x K32 MFMA);
// exp2 -> pack -> DIRECT B-frag of 16x16x16 PV MFMAs (layout identity, no
// cross-lane). l via per-lane VALU sum + 2 end shuffles. 1-deep prefetch.
// K-split NSPLIT across blockIdx.y. grid (49, NHD*NSPLIT, NB) x 256.
__global__ __launch_bounds__(256) void k_flash2(const u16* __restrict__ qc,
                                                const u16* __restrict__ kb,
                                                const u16* __restrict__ vt,
                                                float* __restrict__ op,
                                                float* __restrict__ lp) {
    int b = blockIdx.z;
    int h = blockIdx.y & 3;
    int s = blockIdx.y >> 2;
    int wave = threadIdx.x >> 6, lane = threadIdx.x & 63;
    int c = lane & 15, u = lane >> 4;
    int q0 = blockIdx.x * 64 + wave * 16;
    size_t bh = (size_t)b * NHD + h;
    const u16* kbase = kb + bh * NN * HD;
    const u16* vbase = vt + bh * (size_t)HD * NN;
    short8 qfrag = *(const short8*)(qc + (bh * NN + q0 + c) * HD + u * 8);
    const f32x4 z = {0.f, 0.f, 0.f, 0.f};
    f32x4 o0 = z, o1 = z;
    float lpart = 0.f;
    int t0 = s * 25, t1 = (98 < t0 + 25) ? 98 : t0 + 25;
    // prefetch tile t0
    int kk = t0 * 32;
    short8  kf0 = *(const short8*)(kbase + (size_t)(kk + c) * HD + u * 8);
    short8  kf1 = *(const short8*)(kbase + (size_t)(kk + 16 + c) * HD + u * 8);
    short4v va0 = *(const short4v*)(vbase + (size_t)c * NN + kk + u * 4);
    short4v va1 = *(const short4v*)(vbase + (size_t)c * NN + kk + 16 + u * 4);
    short4v vb0 = *(const short4v*)(vbase + (size_t)(c + 16) * NN + kk + u * 4);
    short4v vb1 = *(const short4v*)(vbase + (size_t)(c + 16) * NN + kk + 16 + u * 4);
    for (int kt = t0; kt < t1; ++kt) {
        int ktn = (kt + 1 < t1) ? kt + 1 : t0;   // clamped prefetch index
        int kn = ktn * 32;
        short8  nkf0 = *(const short8*)(kbase + (size_t)(kn + c) * HD + u * 8);
        short8  nkf1 = *(const short8*)(kbase + (size_t)(kn + 16 + c) * HD + u * 8);
        short4v nva0 = *(const short4v*)(vbase + (size_t)c * NN + kn + u * 4);
        short4v nva1 = *(const short4v*)(vbase + (size_t)c * NN + kn + 16 + u * 4);
        short4v nvb0 = *(const short4v*)(vbase + (size_t)(c + 16) * NN + kn + u * 4);
        short4v nvb1 = *(const short4v*)(vbase + (size_t)(c + 16) * NN + kn + 16 + u * 4);
        f32x4 st0 = __builtin_amdgcn_mfma_f32_16x16x32_bf16(kf0, qfrag, z, 0, 0, 0);
        f32x4 st1 = __builtin_amdgcn_mfma_f32_16x16x32_bf16(kf1, qfrag, z, 0, 0, 0);
        float e00 = __builtin_amdgcn_exp2f(st0[0]);
        float e01 = __builtin_amdgcn_exp2f(st0[1]);
        float e02 = __builtin_amdgcn_exp2f(st0[2]);
        float e03 = __builtin_amdgcn_exp2f(st0[3]);
        float e10 = __builtin_amdgcn_exp2f(st1[0]);
        float e11 = __builtin_amdgcn_exp2f(st1[1]);
        float e12 = __builtin_amdgcn_exp2f(st1[2]);
        float e13 = __builtin_amdgcn_exp2f(st1[3]);
        lpart += (e00 + e01) + (e02 + e03) + (e10 + e11) + (e12 + e13);
        short4v p0 = pack4(e00, e01, e02, e03);
        short4v p1 = pack4(e10, e11, e12, e13);
        o0 = __builtin_amdgcn_mfma_f32_16x16x16bf16_1k(va0, p0, o0, 0, 0, 0);
        o0 = __builtin_amdgcn_mfma_f32_16x16x16bf16_1k(va1, p1, o0, 0, 0, 0);
        o1 = __builtin_amdgcn_mfma_f32_16x16x16bf16_1k(vb0, p0, o1, 0, 0, 0);
        o1 = __builtin_amdgcn_mfma_f32_16x16x16bf16_1k(vb1, p1, o1, 0, 0, 0);
        kf0 = nkf0; kf1 = nkf1;
        va0 = nva0; va1 = nva1; vb0 = nvb0; vb1 = nvb1;
    }
    lpart += __shfl_xor(lpart, 16);
    lpart += __shfl_xor(lpart, 32);
    // O^T frags: lane holds O[q=c][d=u*4+r] (o0: d 0..15, o1: d 16..31)
    float* obase = op + (((size_t)(s * NB + b)) * NN + q0 + c) * NC + h * HD;
    *(f32x4*)&obase[u * 4]      = o0;
    *(f32x4*)&obase[16 + u * 4] = o1;
    if (u == 0)
        lp[(((size_t)(s * NB + b)) * NHD + h) * NN + q0 + c] = lpart;
}

// ---------------------------------------------------------------------------
// combine NSPLIT partials + normalize + proj (fp32) + LayerNorm + NCHW store.
__global__ __launch_bounds__(128) void k_proj_ln(const float* __restrict__ op,
                                                 const float* __restrict__ lp,
                                                 const float* __restrict__ wpt,
                                                 const float* __restrict__ bgb,
                                                 void* __restrict__ out,
                                                 const int* __restrict__ flag) {
    __shared__ float row[NC];
    __shared__ float red[4];
    int bn = blockIdx.x;
    int b = bn / NN, n = bn % NN;
    int o = threadIdx.x;
    int h = o >> 5;
    float lsum = 0.f, oval = 0.f;
#pragma unroll
    for (int s = 0; s < NSPLIT; ++s) {
        lsum += lp[(((size_t)(s * NB + b)) * NHD + h) * NN + n];
        oval += op[(((size_t)(s * NB + b)) * NN + n) * NC + o];
    }
    row[o] = oval / lsum;
    __syncthreads();
    float acc = bgb[o];
#pragma unroll 8
    for (int c = 0; c < NC; ++c) acc += row[c] * wpt[c * NC + o];
    float s1 = acc, s2 = acc * acc;
#pragma unroll
    for (int off = 32; off; off >>= 1) {
        s1 += __shfl_xor(s1, off);
        s2 += __shfl_xor(s2, off);
    }
    if ((o & 63) == 0) { red[(o >> 6) * 2] = s1; red[(o >> 6) * 2 + 1] = s2; }
    __syncthreads();
    float mu  = (red[0] + red[2]) * (1.f / NC);
    float ex2 = (red[1] + red[3]) * (1.f / NC);
    float rstd = rsqrtf(ex2 - mu * mu + 1e-5f);
    float val = (acc - mu) * rstd * bgb[128 + o] + bgb[256 + o];
    size_t oidx = ((size_t)(b * NC + o)) * NN + n;
    if (*flag) ((__hip_bfloat16*)out)[oidx] = __float2bfloat16(val);
    else       ((float*)out)[oidx] = val;
}

// ---------------------------------------------------------------------------
extern "C" void kernel_launch(void* const* d_in, const int* in_sizes, int n_in,
                              void* d_out, int out_size, void* d_ws, size_t ws_size,
                              hipStream_t stream) {
    const void* x_raw  = d_in[0];
    const void* wq_raw = d_in[1];
    const void* wp_raw = d_in[2];
    const void* bp_raw = d_in[3];
    const void* lg_raw = d_in[4];
    const void* lb_raw = d_in[5];

    float* ws   = (float*)d_ws;
    int*   flag = (int*)d_ws;
    float* xf   = ws + 16;                         // 802816 f
    float* wpt  = xf + NB * NC * NN;               // 16384 f
    float* bgb  = wpt + NC * NC;                   // 512 f
    float* op   = bgb + 512;                       // NSPLIT*NB*NN*NC f
    float* lp   = op + (size_t)NSPLIT * NB * NN * NC;  // NSPLIT*NB*NHD*NN f
    u16*   xT   = (u16*)(lp + (size_t)NSPLIT * NB * NHD * NN);
    u16*   wbf  = xT + (size_t)NB * NN * NC;       // 49152 u16
    u16*   qb   = wbf + 3 * NC * NC;               // 802816 u16 each:
    u16*   kbf  = qb + (size_t)NB * NHD * NN * HD;
    u16*   vtb  = kbf + (size_t)NB * NHD * NN * HD;
    u16*   qcb  = vtb + (size_t)NB * NHD * NN * HD;
    u16*   agb  = qcb + (size_t)NB * NHD * NN * HD;  // 16384 u16
    u16*   agT  = agb + NB * NHD * 64 * 32;          // 16384 u16
    // total ~24.7 MB

    k_detect<<<1, 256, 0, stream>>>((const u16*)x_raw, flag);
    k_conv_x<<<dim3(NN / 16, NB), 256, 0, stream>>>(x_raw, xf, xT, flag);
    k_conv_w<<<258, 256, 0, stream>>>(wq_raw, wp_raw, bp_raw, lg_raw, lb_raw,
                                      wbf, wpt, bgb, flag);
    k_qkv2<<<dim3(NN / 64, 6, NB), 256, 0, stream>>>(xT, wbf, qb, kbf, vtb);
    k_agent<<<79, 256, 0, stream>>>(xf, agb, agT);
    k_stage1_2<<<dim3(NN / 64, NHD, NB), 256, 0, stream>>>(qb, agb, agT, qcb);
    k_flash2<<<dim3(NN / 64, NHD * NSPLIT, NB), 256, 0, stream>>>(qcb, kbf, vtb, op, lp);
    k_proj_ln<<<NB * NN, 128, 0, stream>>>(op, lp, wpt, bgb, d_out, flag);
}